// Round 2
// baseline (513.186 us; speedup 1.0000x reference)
//
#include <hip/hip_runtime.h>

#define T_ 50
#define I_ 16
#define H_ 128
#define S_ 32768
#define SPB 64        // sequences per block
#define MT 4          // 16-row M tiles (64/16)
#define ROWB 384      // bytes per LDS state row: K=192 fp16 slots (128 h | 16 x | pad zeros)

typedef _Float16 half8 __attribute__((ext_vector_type(8)));
typedef float f32x4 __attribute__((ext_vector_type(4)));

__device__ inline half8 h8zero() {
  half8 v;
#pragma unroll
  for (int j = 0; j < 8; ++j) v[j] = (_Float16)0.f;
  return v;
}

// Gate order (PyTorch LSTMCell): i,f,g,o -> gate = 128*n + hid
// Wave w owns hid cols [16w,16w+16). A-frag: row=lane&15, k=8*(lane>>4)+j.
// D-frag: col=lane&15, row=4*(lane>>4)+r (m89-verified layout).
__global__ __launch_bounds__(512, 2)
void lstm_fused(const float* __restrict__ seq,   // [S][T][16]
                const float* __restrict__ mask,  // [S][T]
                const float* __restrict__ Wih,   // [512][16]
                const float* __restrict__ Whh,   // [512][128]
                const float* __restrict__ bih,   // [512]
                const float* __restrict__ bhh,   // [512]
                float* __restrict__ out)         // h[S][128] then c[S][128]
{
  // state row r (seq): bytes [0,256) = h (swizzled), [256,288) = x_t, rest zero pad
  __shared__ char  hbuf[2][SPB * ROWB];   // 48 KB, double buffered
  __shared__ float mlds[SPB * T_];        // 12.8 KB, whole mask tile

  const int tid  = threadIdx.x;
  const int wav  = tid >> 6;
  const int lane = tid & 63;
  const int l15  = lane & 15;
  const int lg   = lane >> 4;            // 0..3
  const int sb   = blockIdx.x * SPB;

  const float L2E  = 1.44269504089f;
  const float L2E2 = 2.88539008178f;

  // ---- one-time: W fragments into registers (K padded 144 -> 160, frag 4 zero-tailed) ----
  half8 wf[4][5];
  float nb[4];
#pragma unroll
  for (int n = 0; n < 4; ++n) {
    const int gate = 128 * n + 16 * wav + l15;
#pragma unroll
    for (int ks = 0; ks < 5; ++ks) {
      half8 f = h8zero();
#pragma unroll
      for (int j = 0; j < 8; ++j) {
        const int k = 32 * ks + 8 * lg + j;
        float v = 0.f;
        if (k < 128)      v = Whh[gate * 128 + k];
        else if (k < 144) v = Wih[gate * 16 + (k - 128)];
        f[j] = (_Float16)v;
      }
      wf[n][ks] = f;
    }
    const float bsum = bih[gate] + bhh[gate];
    nb[n] = (n == 2 ? -L2E2 : -L2E) * bsum;   // pre-scaled for exp2
  }

  // ---- preload full mask tile (perfectly coalesced: mlds[i] = mask[sb*50 + i]) ----
#pragma unroll
  for (int i = tid; i < SPB * T_; i += 512) mlds[i] = mask[(size_t)sb * T_ + i];

  // ---- zero both state buffers (zero is swizzle-invariant) ----
#pragma unroll
  for (int i = tid; i < 2 * SPB * ROWB / 16; i += 512) ((int4*)hbuf)[i] = make_int4(0, 0, 0, 0);

  float c_reg[MT][4];
  float h_reg[MT][4];
#pragma unroll
  for (int m = 0; m < MT; ++m)
#pragma unroll
    for (int r = 0; r < 4; ++r) { c_reg[m][r] = 0.f; h_reg[m][r] = 0.f; }

  // x staging geometry: thread handles seq-row xs, elements {2*(tid&7), +1}
  const int xs  = tid >> 3;                 // 0..63
  const int xi2 = (tid & 7) * 4;            // byte offset of the 2-element pair in x region
  const float* xptr = seq + (size_t)(sb + xs) * (T_ * I_) + (tid & 7) * 2;
  const int xdst = xs * ROWB + ((256 + xi2) ^ ((xs & 7) << 4));

  // prologue: stage x_0 into buffer 0
  {
    const float2 xv = *(const float2*)xptr;
    _Float16 hx[2] = {(_Float16)xv.x, (_Float16)xv.y};
    *(int*)&hbuf[0][xdst] = *(int*)hx;
  }
  __syncthreads();

#pragma unroll 1
  for (int t = 0; t < T_; ++t) {
    const int p = t & 1;
    const char* __restrict__ rd = hbuf[p];
    char* __restrict__       wr = hbuf[p ^ 1];

    // 1. issue next x load early (HBM latency hides under MFMA phase)
    float2 xv;
    if (t < T_ - 1) xv = *(const float2*)(xptr + (t + 1) * I_);

    // 2. gates = [h|x|pad] @ Wcomb^T
    f32x4 acc[MT][4];
#pragma unroll
    for (int m = 0; m < MT; ++m)
#pragma unroll
      for (int n = 0; n < 4; ++n) { f32x4 z = {0.f, 0.f, 0.f, 0.f}; acc[m][n] = z; }

#pragma unroll
    for (int m = 0; m < MT; ++m) {
      const int row = 16 * m + l15;
      const int swz = (row & 7) << 4;
      half8 a[5];
#pragma unroll
      for (int ks = 0; ks < 5; ++ks)
        a[ks] = *(const half8*)(rd + row * ROWB + ((64 * ks + 16 * lg) ^ swz));
#pragma unroll
      for (int n = 0; n < 4; ++n)
#pragma unroll
        for (int ks = 0; ks < 5; ++ks)
          acc[m][n] = __builtin_amdgcn_mfma_f32_16x16x32_f16(a[ks], wf[n][ks], acc[m][n], 0, 0, 0);
    }

    // 3. LSTM cell update (5 exp + 2 rcp per hidden unit), write h' to other buffer
#pragma unroll
    for (int m = 0; m < MT; ++m) {
#pragma unroll
      for (int r = 0; r < 4; ++r) {
        const int row = 16 * m + 4 * lg + r;    // local seq index
        const float iv = acc[m][0][r];
        const float fv = acc[m][1][r];
        const float gv = acc[m][2][r];
        const float ov = acc[m][3][r];
        const float ei = __builtin_amdgcn_exp2f(fminf(fmaf(iv, -L2E,  nb[0]), 30.f));
        const float ef = __builtin_amdgcn_exp2f(fminf(fmaf(fv, -L2E,  nb[1]), 30.f));
        const float eg = __builtin_amdgcn_exp2f(fminf(fmaf(gv, -L2E2, nb[2]), 30.f));
        const float eo = __builtin_amdgcn_exp2f(fminf(fmaf(ov, -L2E,  nb[3]), 30.f));
        const float pii = 1.f + ei, pif = 1.f + ef, pig = 1.f + eg, pio = 1.f + eo;
        // c' = sig(f)*c + sig(i)*tanh(g) = [c*pii*pig + (1-eg)*pif] / (pif*pii*pig)
        const float mig = pii * pig;
        const float num = fmaf(c_reg[m][r], mig, (1.f - eg) * pif);
        const float cn  = num * __builtin_amdgcn_rcpf(mig * pif);
        // h' = sig(o)*tanh(c'): ec = exp(-2c'), tanh = (1-ec)/(1+ec)
        const float ec  = __builtin_amdgcn_exp2f(fminf(cn * -L2E2, 30.f));
        const float hn  = (1.f - ec) * __builtin_amdgcn_rcpf(pio * (1.f + ec));
        // mask blend
        const float mk = mlds[row * T_ + t];
        const float hN = fmaf(mk, hn - h_reg[m][r], h_reg[m][r]);
        const float cN = fmaf(mk, cn - c_reg[m][r], c_reg[m][r]);
        h_reg[m][r] = hN;
        c_reg[m][r] = cN;
        // h' (fp16) into next buffer's swizzled h region
        const int cb = (32 * wav + 2 * l15) ^ ((row & 7) << 4);
        *(_Float16*)(wr + row * ROWB + cb) = (_Float16)hN;
      }
    }

    // 4. stage x_{t+1} into next buffer's x region
    if (t < T_ - 1) {
      _Float16 hx[2] = {(_Float16)xv.x, (_Float16)xv.y};
      *(int*)(wr + xdst) = *(int*)hx;
    }

    // 5. the only barrier of the step
    __syncthreads();
  }

  // ---- final h, c -> out ----
#pragma unroll
  for (int m = 0; m < MT; ++m)
#pragma unroll
    for (int r = 0; r < 4; ++r) {
      const size_t s = (size_t)sb + 16 * m + 4 * lg + r;
      const int hc = 16 * wav + l15;
      out[s * H_ + hc] = h_reg[m][r];
      out[(size_t)S_ * H_ + s * H_ + hc] = c_reg[m][r];
    }
}

extern "C" void kernel_launch(void* const* d_in, const int* in_sizes, int n_in,
                              void* d_out, int out_size, void* d_ws, size_t ws_size,
                              hipStream_t stream) {
  const float* seq  = (const float*)d_in[0];
  const float* mask = (const float*)d_in[1];
  const float* Wih  = (const float*)d_in[2];
  const float* Whh  = (const float*)d_in[3];
  const float* bih  = (const float*)d_in[4];
  const float* bhh  = (const float*)d_in[5];
  float* out = (float*)d_out;
  lstm_fused<<<dim3(S_ / SPB), dim3(512), 0, stream>>>(seq, mask, Wih, Whh, bih, bhh, out);
}

// Round 5
// 477.024 us; speedup vs baseline: 1.0758x; 1.0758x over previous
//
#include <hip/hip_runtime.h>

#define T_ 50
#define I_ 16
#define H_ 128
#define S_ 32768
#define SPB 64          // sequences per block
#define MT 4            // 16-row M tiles (64/16)
#define ROWB 384        // bytes per LDS state row (K=192 fp16 slots: 128 h | 16 x | pad)
#define BSTR 32768      // state buffer stride (bit-15 XOR toggle)
#define MOFF (2*BSTR)   // mask region offset in LDS

typedef _Float16 half8 __attribute__((ext_vector_type(8)));
typedef float f32x4 __attribute__((ext_vector_type(4)));

__device__ inline half8 h8zero() {
  half8 v;
#pragma unroll
  for (int j = 0; j < 8; ++j) v[j] = (_Float16)0.f;
  return v;
}

// Gate order (PyTorch LSTMCell): i,f,g,o -> gate = 128*n + hid
// Wave w owns hid cols [16w,16w+16). A-frag: row=lane&15, k=8*(lane>>4)+j.
// D-frag: col=lane&15, row=4*(lane>>4)+r (m89-verified layout).
__global__ __launch_bounds__(512, 2)
void lstm_fused(const float* __restrict__ seq,   // [S][T][16]
                const float* __restrict__ mask,  // [S][T]
                const float* __restrict__ Wih,   // [512][16]
                const float* __restrict__ Whh,   // [512][128]
                const float* __restrict__ bih,   // [512]
                const float* __restrict__ bhh,   // [512]
                float* __restrict__ out)         // h[S][128] then c[S][128]
{
  __shared__ char lds[MOFF + T_ * SPB * 4];   // 78336 B: 2 state bufs + mask[t][s]

  const int tid  = threadIdx.x;
  const int wav  = tid >> 6;
  const int lane = tid & 63;
  const int l15  = lane & 15;
  const int lg   = lane >> 4;            // 0..3
  const int sb   = blockIdx.x * SPB;

  const float L2E  = 1.44269504089f;
  const float L2E2 = 2.88539008178f;

  // ---- one-time: W fragments into registers (K padded 144 -> 160, frag 4 zero-tailed) ----
  half8 wf[4][5];
  float nb[4];
#pragma unroll
  for (int n = 0; n < 4; ++n) {
    const int gate = 128 * n + 16 * wav + l15;
#pragma unroll
    for (int ks = 0; ks < 5; ++ks) {
      half8 f = h8zero();
#pragma unroll
      for (int j = 0; j < 8; ++j) {
        const int k = 32 * ks + 8 * lg + j;
        float v = 0.f;
        if (k < 128)      v = Whh[gate * 128 + k];
        else if (k < 144) v = Wih[gate * 16 + (k - 128)];
        f[j] = (_Float16)v;
      }
      wf[n][ks] = f;
    }
    nb[n] = (n == 2 ? -L2E2 : -L2E) * (bih[gate] + bhh[gate]);   // pre-scaled for exp2
  }

  // ---- mask transposed into LDS: mlds[t][s] (one-time) ----
  {
    const int s = tid >> 3;
    const float* mp = mask + (size_t)(sb + s) * T_;
#pragma unroll 1
    for (int t = tid & 7; t < T_; t += 8)
      *(float*)(lds + MOFF + t * 256 + s * 4) = mp[t];
  }
  // ---- zero both state buffers ----
#pragma unroll 1
  for (int i = tid; i < 2 * BSTR / 16; i += 512) ((int4*)lds)[i] = make_int4(0, 0, 0, 0);

  float c_reg[MT][4];
  float h_reg[MT][4];
#pragma unroll
  for (int m = 0; m < MT; ++m)
#pragma unroll
    for (int r = 0; r < 4; ++r) { c_reg[m][r] = 0.f; h_reg[m][r] = 0.f; }

  // ---- hoisted LDS addresses (m folded into immediate offsets of 6144*m) ----
  int rdo[5];                                   // A-frag reads: row = 16m + l15
  const int swzr = (l15 & 7) << 4;
#pragma unroll
  for (int ks = 0; ks < 5; ++ks) rdo[ks] = l15 * ROWB + ((64 * ks + 16 * lg) ^ swzr);
  int wro[4];                                   // h' writes: row = 16m + 4lg + r (starts in buf1)
#pragma unroll
  for (int r = 0; r < 4; ++r) {
    const int row = 4 * lg + r;
    wro[r] = BSTR + row * ROWB + ((32 * wav + 2 * l15) ^ ((row & 7) << 4));
  }
  const int xs = tid >> 3, xq = tid & 7;        // x staging: row xs, elems {2xq, 2xq+1}
  int xwo = BSTR + xs * ROWB + ((256 + 4 * xq) ^ ((xs & 7) << 4));
  int mo  = MOFF + 16 * lg;                     // mask read base (+=256 per step)

  const float* xptr = seq + (size_t)(sb + xs) * (T_ * I_) + 2 * xq;

  __syncthreads();   // zero/mask staging done
  // prologue: stage x_0 into buffer 0
  {
    const float2 xv = *(const float2*)xptr;
    _Float16 hx[2] = {(_Float16)xv.x, (_Float16)xv.y};
    *(int*)(lds + (xwo ^ BSTR)) = *(int*)hx;
  }
  __syncthreads();

  auto loadA = [&](half8* a, int mb) {
#pragma unroll
    for (int ks = 0; ks < 5; ++ks)
      a[ks] = *(const half8*)(lds + (rdo[ks] + mb));
  };
  auto runM = [&](const half8* a, f32x4* ac) {
#pragma unroll
    for (int ks = 0; ks < 5; ++ks)
#pragma unroll
      for (int n = 0; n < 4; ++n)
        ac[n] = __builtin_amdgcn_mfma_f32_16x16x32_f16(a[ks], wf[n][ks], ac[n], 0, 0, 0);
  };
  auto zero4 = [&](f32x4* ac) {
    f32x4 z = {0.f, 0.f, 0.f, 0.f};
    ac[0] = z; ac[1] = z; ac[2] = z; ac[3] = z;
  };
  auto updM = [&](int m, const f32x4* ac) {
    const f32x4 mv = *(const f32x4*)(lds + (mo + 64 * m));
#pragma unroll
    for (int r = 0; r < 4; ++r) {
      const float iv = ac[0][r], fv = ac[1][r], gv = ac[2][r], ov = ac[3][r];
      const float ei = __builtin_amdgcn_exp2f(fminf(fmaf(iv, -L2E,  nb[0]), 30.f));
      const float ef = __builtin_amdgcn_exp2f(fminf(fmaf(fv, -L2E,  nb[1]), 30.f));
      const float eg = __builtin_amdgcn_exp2f(fminf(fmaf(gv, -L2E2, nb[2]), 30.f));
      const float eo = __builtin_amdgcn_exp2f(fminf(fmaf(ov, -L2E,  nb[3]), 30.f));
      const float pii = 1.f + ei, pif = 1.f + ef, pig = 1.f + eg, pio = 1.f + eo;
      // c' = sig(f)*c + sig(i)*tanh(g) = [c*pii*pig + (1-eg)*pif] / (pif*pii*pig)
      const float mig = pii * pig;
      const float num = fmaf(c_reg[m][r], mig, (1.f - eg) * pif);
      const float cn  = num * __builtin_amdgcn_rcpf(mig * pif);
      // h' = sig(o)*tanh(c'): ec = exp(-2c')
      const float ec  = __builtin_amdgcn_exp2f(fminf(cn * -L2E2, 30.f));
      const float hn  = (1.f - ec) * __builtin_amdgcn_rcpf(pio * (1.f + ec));
      const float mk  = mv[r];
      const float hN  = fmaf(mk, hn - h_reg[m][r], h_reg[m][r]);
      const float cN  = fmaf(mk, cn - c_reg[m][r], c_reg[m][r]);
      h_reg[m][r] = hN;
      c_reg[m][r] = cN;
      *(_Float16*)(lds + (wro[r] + 6144 * m)) = (_Float16)hN;
    }
  };

#pragma unroll 1
  for (int t = 0; t < T_; ++t) {
    // 1. next x load issued early (latency hides under compute)
    float2 xv;
    if (t < T_ - 1) xv = *(const float2*)(xptr + (t + 1) * I_);

    // 2. skewed pipeline over the 4 M-tiles: MFMA(m+1) overlaps update(m)
    half8 aA[5], aB[5];
    f32x4 acA[4], acB[4];
    loadA(aA, 0);                       // m0 frags
    loadA(aB, 6144);                    // m1 frags
    zero4(acA); runM(aA, acA);          // m0 MFMA
    loadA(aA, 12288);                   // m2 frags
    zero4(acB); runM(aB, acB);          // m1 MFMA
    updM(0, acA);                       // m0 update (VALU, overlaps m1/m2 MFMA)
    zero4(acA); runM(aA, acA);          // m2 MFMA
    loadA(aB, 18432);                   // m3 frags
    updM(1, acB);                       // m1 update
    zero4(acB); runM(aB, acB);          // m3 MFMA
    updM(2, acA);                       // m2 update
    updM(3, acB);                       // m3 update

    // 3. stage x_{t+1} into the buffer being written
    if (t < T_ - 1) {
      _Float16 hx[2] = {(_Float16)xv.x, (_Float16)xv.y};
      *(int*)(lds + xwo) = *(int*)hx;
    }

    // 4. single barrier per step, then toggle buffers (bit-15 XOR) / advance mask
    __syncthreads();
#pragma unroll
    for (int ks = 0; ks < 5; ++ks) rdo[ks] ^= BSTR;
#pragma unroll
    for (int r = 0; r < 4; ++r) wro[r] ^= BSTR;
    xwo ^= BSTR;
    mo += 256;
  }

  // ---- final h, c -> out ----
#pragma unroll
  for (int m = 0; m < MT; ++m)
#pragma unroll
    for (int r = 0; r < 4; ++r) {
      const size_t s = (size_t)sb + 16 * m + 4 * lg + r;
      const int hc = 16 * wav + l15;
      out[s * H_ + hc] = h_reg[m][r];
      out[(size_t)S_ * H_ + s * H_ + hc] = c_reg[m][r];
    }
}

extern "C" void kernel_launch(void* const* d_in, const int* in_sizes, int n_in,
                              void* d_out, int out_size, void* d_ws, size_t ws_size,
                              hipStream_t stream) {
  const float* seq  = (const float*)d_in[0];
  const float* mask = (const float*)d_in[1];
  const float* Wih  = (const float*)d_in[2];
  const float* Whh  = (const float*)d_in[3];
  const float* bih  = (const float*)d_in[4];
  const float* bhh  = (const float*)d_in[5];
  float* out = (float*)d_out;
  lstm_fused<<<dim3(S_ / SPB), dim3(512), 0, stream>>>(seq, mask, Wih, Whh, bih, bhh, out);
}

// Round 13
// 465.326 us; speedup vs baseline: 1.1029x; 1.0251x over previous
//
#include <hip/hip_runtime.h>

#define T_ 50
#define I_ 16
#define H_ 128
#define S_ 32768
#define SPB 64          // sequences per block
#define MT 4            // 16-row M tiles (64/16)
#define ROWB 384        // bytes per LDS state row (K=192 fp16 slots: 128 h | 16 x | pad)
#define BSTR 32768      // state buffer stride (bit-15 XOR toggle)
#define MOFF (2*BSTR)   // mask region offset in LDS

typedef _Float16 half8 __attribute__((ext_vector_type(8)));
typedef float f32x4 __attribute__((ext_vector_type(4)));
typedef float f32x2 __attribute__((ext_vector_type(2)));

__device__ inline half8 h8zero() {
  half8 v;
#pragma unroll
  for (int j = 0; j < 8; ++j) v[j] = (_Float16)0.f;
  return v;
}

// Gate order (PyTorch LSTMCell): i,f,g,o -> gate = 128*n + hid
// Wave w owns hid cols [16w,16w+16). A-frag: row=lane&15, k=8*(lane>>4)+j.
// D-frag: col=lane&15, row=4*(lane>>4)+r (m89-verified layout).
__global__ __launch_bounds__(512, 2)
void lstm_fused(const float* __restrict__ seq,   // [S][T][16]
                const float* __restrict__ mask,  // [S][T]
                const float* __restrict__ Wih,   // [512][16]
                const float* __restrict__ Whh,   // [512][128]
                const float* __restrict__ bih,   // [512]
                const float* __restrict__ bhh,   // [512]
                float* __restrict__ out)         // h[S][128] then c[S][128]
{
  __shared__ char lds[MOFF + T_ * SPB * 4];   // 78336 B: 2 state bufs + mask[t][s]

  const int tid  = threadIdx.x;
  const int wav  = tid >> 6;
  const int lane = tid & 63;
  const int l15  = lane & 15;
  const int lg   = lane >> 4;            // 0..3
  const int sb   = blockIdx.x * SPB;

  const float L2E  = 1.44269504089f;
  const float L2E2 = 2.88539008178f;

  // ---- one-time: W fragments into registers (K padded 144 -> 160, frag 4 zero-tailed) ----
  half8 wf[4][5];
  f32x2 vnb[4];
#pragma unroll
  for (int n = 0; n < 4; ++n) {
    const int gate = 128 * n + 16 * wav + l15;
#pragma unroll
    for (int ks = 0; ks < 5; ++ks) {
      half8 f = h8zero();
#pragma unroll
      for (int j = 0; j < 8; ++j) {
        const int k = 32 * ks + 8 * lg + j;
        float v = 0.f;
        if (k < 128)      v = Whh[gate * 128 + k];
        else if (k < 144) v = Wih[gate * 16 + (k - 128)];
        f[j] = (_Float16)v;
      }
      wf[n][ks] = f;
    }
    const float nbs = (n == 2 ? -L2E2 : -L2E) * (bih[gate] + bhh[gate]);   // pre-scaled for exp2
    vnb[n].x = nbs; vnb[n].y = nbs;
  }

  // ---- mask transposed into LDS: mlds[t][s] (one-time) ----
  {
    const int s = tid >> 3;
    const float* mp = mask + (size_t)(sb + s) * T_;
#pragma unroll 1
    for (int t = tid & 7; t < T_; t += 8)
      *(float*)(lds + MOFF + t * 256 + s * 4) = mp[t];
  }
  // ---- zero both state buffers ----
#pragma unroll 1
  for (int i = tid; i < 2 * BSTR / 16; i += 512) ((int4*)lds)[i] = make_int4(0, 0, 0, 0);

  f32x2 c2[MT][2];   // c/h state as pairs: [m][p] holds rows 16m+4lg+{2p,2p+1}
  f32x2 h2[MT][2];
#pragma unroll
  for (int m = 0; m < MT; ++m)
#pragma unroll
    for (int p = 0; p < 2; ++p) { c2[m][p] = (f32x2){0.f, 0.f}; h2[m][p] = (f32x2){0.f, 0.f}; }

  // ---- hoisted LDS addresses (m folded into immediate offsets of 6144*m) ----
  int rdo[5];                                   // A-frag reads: row = 16m + l15
  const int swzr = (l15 & 7) << 4;
#pragma unroll
  for (int ks = 0; ks < 5; ++ks) rdo[ks] = l15 * ROWB + ((64 * ks + 16 * lg) ^ swzr);
  int wro[4];                                   // h' writes: row = 16m + 4lg + r (starts in buf1)
#pragma unroll
  for (int r = 0; r < 4; ++r) {
    const int row = 4 * lg + r;
    wro[r] = BSTR + row * ROWB + ((32 * wav + 2 * l15) ^ ((row & 7) << 4));
  }
  const int xs = tid >> 3, xq = tid & 7;        // x staging: row xs, elems {2xq, 2xq+1}
  int xwo = BSTR + xs * ROWB + ((256 + 4 * xq) ^ ((xs & 7) << 4));
  int mo  = MOFF + 16 * lg;                     // mask read base (+=256 per step)

  const float* xptr = seq + (size_t)(sb + xs) * (T_ * I_) + 2 * xq;

  __syncthreads();   // zero/mask staging done
  // prologue: stage x_0 into buffer 0
  {
    const float2 xv = *(const float2*)xptr;
    _Float16 hx[2] = {(_Float16)xv.x, (_Float16)xv.y};
    *(int*)(lds + (xwo ^ BSTR)) = *(int*)hx;
  }
  __syncthreads();

  auto loadA = [&](half8* a, int mb) {
#pragma unroll
    for (int ks = 0; ks < 5; ++ks)
      a[ks] = *(const half8*)(lds + (rdo[ks] + mb));
  };
  auto runM = [&](const half8* a, f32x4* ac) {
#pragma unroll
    for (int ks = 0; ks < 5; ++ks)
#pragma unroll
      for (int n = 0; n < 4; ++n)
        ac[n] = __builtin_amdgcn_mfma_f32_16x16x32_f16(a[ks], wf[n][ks], ac[n], 0, 0, 0);
  };
  auto zero4 = [&](f32x4* ac) {
    f32x4 z = {0.f, 0.f, 0.f, 0.f};
    ac[0] = z; ac[1] = z; ac[2] = z; ac[3] = z;
  };
  // Cell update on element PAIRS (packed f32 VALU; paired-rcp: 6 trans/elem)
  auto updM = [&](int m, const f32x4* ac) {
    const f32x4 mv = *(const f32x4*)(lds + (mo + 64 * m));
    const f32x2 one   = {1.f, 1.f};
    const f32x2 vnL2E = {-L2E, -L2E};
    const f32x2 vnL2E2= {-L2E2, -L2E2};
    const f32x2 vclmp = {30.f, 30.f};
#pragma unroll
    for (int p = 0; p < 2; ++p) {
      const f32x2 iv = {ac[0][2*p], ac[0][2*p+1]};
      const f32x2 fv = {ac[1][2*p], ac[1][2*p+1]};
      const f32x2 gv = {ac[2][2*p], ac[2][2*p+1]};
      const f32x2 ov = {ac[3][2*p], ac[3][2*p+1]};
      const f32x2 ai = __builtin_elementwise_fma(iv, vnL2E,  vnb[0]);
      const f32x2 af = __builtin_elementwise_fma(fv, vnL2E,  vnb[1]);
      const f32x2 ag = __builtin_elementwise_fma(gv, vnL2E2, vnb[2]);
      const f32x2 ao = __builtin_elementwise_fma(ov, vnL2E,  vnb[3]);
      f32x2 ei, ef, eg, eo;
      ei.x = __builtin_amdgcn_exp2f(ai.x); ei.y = __builtin_amdgcn_exp2f(ai.y);
      ef.x = __builtin_amdgcn_exp2f(af.x); ef.y = __builtin_amdgcn_exp2f(af.y);
      eg.x = __builtin_amdgcn_exp2f(ag.x); eg.y = __builtin_amdgcn_exp2f(ag.y);
      eo.x = __builtin_amdgcn_exp2f(ao.x); eo.y = __builtin_amdgcn_exp2f(ao.y);
      const f32x2 pii = one + ei, pif = one + ef, pig = one + eg, pio = one + eo;
      // c' = [c*pii*pig + (1-eg)*pif] / (pii*pig*pif), paired rcp across the 2 elems
      const f32x2 mig = pii * pig;
      const f32x2 num = __builtin_elementwise_fma(c2[m][p], mig, (one - eg) * pif);
      const f32x2 den = mig * pif;
      const float rd  = __builtin_amdgcn_rcpf(den.x * den.y);
      const f32x2 dsw = {den.y, den.x};
      const f32x2 cn  = num * (dsw * rd);
      // h' = sig(o)*tanh(c') = (1-ec) / (pio*(1+ec)), ec=exp(-2c'), paired rcp
      const f32x2 eca = __builtin_elementwise_min(cn * vnL2E2, vclmp);
      f32x2 ec;
      ec.x = __builtin_amdgcn_exp2f(eca.x); ec.y = __builtin_amdgcn_exp2f(eca.y);
      const f32x2 t1 = one - ec;
      const f32x2 hd = pio * (one + ec);
      const float rh  = __builtin_amdgcn_rcpf(hd.x * hd.y);
      const f32x2 hsw = {hd.y, hd.x};
      const f32x2 hn  = t1 * (hsw * rh);
      // mask blend
      const f32x2 mk = {mv[2*p], mv[2*p+1]};
      const f32x2 hN = __builtin_elementwise_fma(mk, hn - h2[m][p], h2[m][p]);
      const f32x2 cN = __builtin_elementwise_fma(mk, cn - c2[m][p], c2[m][p]);
      h2[m][p] = hN; c2[m][p] = cN;
      *(_Float16*)(lds + (wro[2*p]     + 6144 * m)) = (_Float16)hN.x;
      *(_Float16*)(lds + (wro[2*p + 1] + 6144 * m)) = (_Float16)hN.y;
    }
  };

#pragma unroll 1
  for (int t = 0; t < T_; ++t) {
    // 1. next x load issued early (latency hides under compute)
    float2 xv;
    if (t < T_ - 1) xv = *(const float2*)(xptr + (t + 1) * I_);

    // 2. skewed pipeline over the 4 M-tiles: MFMA(m+1) overlaps update(m)
    half8 aA[5], aB[5];
    f32x4 acA[4], acB[4];
    loadA(aA, 0);                       // m0 frags
    loadA(aB, 6144);                    // m1 frags
    zero4(acA); runM(aA, acA);          // m0 MFMA
    loadA(aA, 12288);                   // m2 frags
    zero4(acB); runM(aB, acB);          // m1 MFMA
    updM(0, acA);                       // m0 update (VALU, overlaps m1/m2 MFMA)
    zero4(acA); runM(aA, acA);          // m2 MFMA
    loadA(aB, 18432);                   // m3 frags
    updM(1, acB);                       // m1 update
    zero4(acB); runM(aB, acB);          // m3 MFMA
    updM(2, acA);                       // m2 update
    updM(3, acB);                       // m3 update

    // 3. stage x_{t+1} into the buffer being written
    if (t < T_ - 1) {
      _Float16 hx[2] = {(_Float16)xv.x, (_Float16)xv.y};
      *(int*)(lds + xwo) = *(int*)hx;
    }

    // 4. single barrier per step, then toggle buffers (bit-15 XOR) / advance mask
    __syncthreads();
#pragma unroll
    for (int ks = 0; ks < 5; ++ks) rdo[ks] ^= BSTR;
#pragma unroll
    for (int r = 0; r < 4; ++r) wro[r] ^= BSTR;
    xwo ^= BSTR;
    mo += 256;
  }

  // ---- final h, c -> out ----
#pragma unroll
  for (int m = 0; m < MT; ++m)
#pragma unroll
    for (int p = 0; p < 2; ++p)
#pragma unroll
      for (int e = 0; e < 2; ++e) {
        const size_t s = (size_t)sb + 16 * m + 4 * lg + 2 * p + e;
        const int hc = 16 * wav + l15;
        out[s * H_ + hc] = h2[m][p][e];
        out[(size_t)S_ * H_ + s * H_ + hc] = c2[m][p][e];
      }
}

extern "C" void kernel_launch(void* const* d_in, const int* in_sizes, int n_in,
                              void* d_out, int out_size, void* d_ws, size_t ws_size,
                              hipStream_t stream) {
  const float* seq  = (const float*)d_in[0];
  const float* mask = (const float*)d_in[1];
  const float* Wih  = (const float*)d_in[2];
  const float* Whh  = (const float*)d_in[3];
  const float* bih  = (const float*)d_in[4];
  const float* bhh  = (const float*)d_in[5];
  float* out = (float*)d_out;
  lstm_fused<<<dim3(S_ / SPB), dim3(512), 0, stream>>>(seq, mask, Wih, Whh, bih, bhh, out);
}